// Round 2
// baseline (2650.084 us; speedup 1.0000x reference)
//
#include <hip/hip_runtime.h>
#include <hip/hip_bf16.h>

// ---------------------------------------------------------------------------
// MultiHopGATv2: 3-layer GATv2 (H=4), N=50000 nodes, E=512000 edges + N self
// loops. Strategy: per-layer, per-head:
//   gemm2:        xl = X @ Wl_h + bl_h ; xr = X @ Wr_h + br_h      [N,C]
//   edge_logits:  logit[e] = att_h . lrelu(xl[src]+xr[dst])        [E']
//   node_pass:    CSR gather per dst node: max, denom, weighted sum
// CSR over dst built once per launch (graph fixed within a call).
// All fp32; tolerance is ~2% of ref absmax so this is comfortably exact.
// ---------------------------------------------------------------------------

#define WAVE 64

// ---------------- CSR build ----------------

__global__ void zero_int_k(int* p, int n) {
    int i = blockIdx.x * 256 + threadIdx.x;
    if (i < n) p[i] = 0;
}

__global__ void count_k(const int* __restrict__ dst, int* __restrict__ cnt,
                        int E, int EP) {
    int e = blockIdx.x * 256 + threadIdx.x;
    if (e >= EP) return;
    int d = (e < E) ? dst[e] : (e - E);
    atomicAdd(&cnt[d], 1);
}

// inclusive scan per 1024-block; offs[g+1] = block-local inclusive; partial[b]=block total
__global__ void scan1_k(const int* __restrict__ cnt, int* __restrict__ offs,
                        int* __restrict__ partial, int N) {
    __shared__ int buf[2][1024];
    int g = blockIdx.x * 1024 + threadIdx.x;
    int v = (g < N) ? cnt[g] : 0;
    int pi = 0;
    buf[0][threadIdx.x] = v;
    __syncthreads();
    for (int s = 1; s < 1024; s <<= 1) {
        int t = buf[pi][threadIdx.x];
        if ((int)threadIdx.x >= s) t += buf[pi][threadIdx.x - s];
        buf[pi ^ 1][threadIdx.x] = t;
        pi ^= 1;
        __syncthreads();
    }
    int incl = buf[pi][threadIdx.x];
    if (g < N) offs[g + 1] = incl;
    if (threadIdx.x == 1023) partial[blockIdx.x] = incl;
}

__global__ void scan2_k(int* partial, int nb) {
    if (blockIdx.x == 0 && threadIdx.x == 0) {
        int run = 0;
        for (int i = 0; i < nb; i++) { int t = partial[i]; partial[i] = run; run += t; }
    }
}

__global__ void scan3_k(int* __restrict__ offs, const int* __restrict__ partial, int N) {
    int g = blockIdx.x * 1024 + threadIdx.x;
    if (g < N) offs[g + 1] += partial[blockIdx.x];
    if (g == 0) offs[0] = 0;
}

__global__ void copy_int_k(const int* __restrict__ a, int* __restrict__ b, int n) {
    int i = blockIdx.x * 256 + threadIdx.x;
    if (i < n) b[i] = a[i];
}

__global__ void fill_k(const int* __restrict__ dst, int* __restrict__ cursor,
                       int* __restrict__ eidx, int E, int EP) {
    int e = blockIdx.x * 256 + threadIdx.x;
    if (e >= EP) return;
    int d = (e < E) ? dst[e] : (e - E);
    int p = atomicAdd(&cursor[d], 1);
    eidx[p] = e;
}

// ---------------- dense transforms (xl, xr for one head) ----------------
// Y1 = X @ Wl[:, colOff:colOff+C] + bl[colOff..], Y2 same with Wr/br.
template <int FIN, int C>
__global__ void gemm2_k(const float* __restrict__ X,
                        const float* __restrict__ Wl, const float* __restrict__ bl,
                        const float* __restrict__ Wr, const float* __restrict__ br,
                        float* __restrict__ xl, float* __restrict__ xr,
                        int N, int HC, int colOff) {
    constexpr int RG   = 256 / C;   // row groups per block (4 for C=64, 2 for C=128)
    constexpr int RPT  = 8;         // rows per thread
    constexpr int ROWS = RG * RPT;  // 32 or 16
    __shared__ float Xs[ROWS][FIN];
    int tid  = threadIdx.x;
    int row0 = blockIdx.x * ROWS;
    for (int i = tid; i < ROWS * FIN; i += 256) {
        int r = i / FIN, k = i % FIN;
        int gr = row0 + r;
        Xs[r][k] = (gr < N) ? X[(size_t)gr * FIN + k] : 0.f;
    }
    __syncthreads();
    int c  = tid % C;
    int rg = tid / C;
    float a1[RPT], a2[RPT];
    float bb1 = bl[colOff + c], bb2 = br[colOff + c];
#pragma unroll
    for (int i = 0; i < RPT; i++) { a1[i] = bb1; a2[i] = bb2; }
    for (int k = 0; k < FIN; k++) {
        float w1 = Wl[(size_t)k * HC + colOff + c];
        float w2 = Wr[(size_t)k * HC + colOff + c];
#pragma unroll
        for (int i = 0; i < RPT; i++) {
            float xv = Xs[rg * RPT + i][k];  // broadcast within wave
            a1[i] = fmaf(xv, w1, a1[i]);
            a2[i] = fmaf(xv, w2, a2[i]);
        }
    }
#pragma unroll
    for (int i = 0; i < RPT; i++) {
        int gr = row0 + rg * RPT + i;
        if (gr < N) {
            xl[(size_t)gr * C + c] = a1[i];
            xr[(size_t)gr * C + c] = a2[i];
        }
    }
}

// ---------------- edge logits: one wave per edge ----------------
template <int C>
__global__ void edge_logits_k(const float* __restrict__ xl, const float* __restrict__ xr,
                              const int* __restrict__ src, const int* __restrict__ dst,
                              const float* __restrict__ att,  // att_i + h*C
                              float* __restrict__ logits, int E, int EP) {
    int wv   = (int)((blockIdx.x * (unsigned)blockDim.x + threadIdx.x) >> 6);
    int lane = threadIdx.x & 63;
    if (wv >= EP) return;
    int s, d;
    if (wv < E) { s = src[wv]; d = dst[wv]; }
    else        { s = wv - E;  d = s; }
    float v = 0.f;
#pragma unroll
    for (int p = 0; p < C / 64; p++) {
        int cc = p * 64 + lane;
        float a = xl[(size_t)s * C + cc] + xr[(size_t)d * C + cc];
        a = (a > 0.f) ? a : 0.2f * a;
        v = fmaf(a, att[cc], v);
    }
#pragma unroll
    for (int o = 32; o > 0; o >>= 1) v += __shfl_xor(v, o, 64);
    if (lane == 0) logits[wv] = v;
}

// ---------------- node pass: softmax over incoming edges + aggregate ----------------
// MODE: 0 = overwrite, 1 = add, 2 = add+finalize(+relu), 3 = add+finalize(no relu)
template <int C, int MODE>
__global__ void node_pass_k(const float* __restrict__ xl, const float* __restrict__ logits,
                            const int* __restrict__ src,
                            const int* __restrict__ offs, const int* __restrict__ eidx,
                            const float* __restrict__ bias,
                            float* __restrict__ out, int N, int E) {
    int wv   = (int)((blockIdx.x * (unsigned)blockDim.x + threadIdx.x) >> 6);
    int lane = threadIdx.x & 63;
    if (wv >= N) return;
    int o0 = offs[wv], o1 = offs[wv + 1];
    // 1) max over incoming logits
    float m = -1e30f;
    for (int j = o0 + lane; j < o1; j += 64) m = fmaxf(m, logits[eidx[j]]);
#pragma unroll
    for (int o = 32; o > 0; o >>= 1) m = fmaxf(m, __shfl_xor(m, o, 64));
    // 2) softmax denominator
    float sm = 0.f;
    for (int j = o0 + lane; j < o1; j += 64) sm += __expf(logits[eidx[j]] - m);
#pragma unroll
    for (int o = 32; o > 0; o >>= 1) sm += __shfl_xor(sm, o, 64);
    float inv = 1.f / sm;
    // 3) weighted aggregation of xl[src]
    constexpr int PERL = C / 64;
    float acc[PERL];
#pragma unroll
    for (int p = 0; p < PERL; p++) acc[p] = 0.f;
    for (int j = o0; j < o1; j++) {
        int eid = eidx[j];
        float w = __expf(logits[eid] - m) * inv;
        int s = (eid < E) ? src[eid] : (eid - E);
#pragma unroll
        for (int p = 0; p < PERL; p++)
            acc[p] = fmaf(w, xl[(size_t)s * C + p * 64 + lane], acc[p]);
    }
#pragma unroll
    for (int p = 0; p < PERL; p++) {
        size_t idx = (size_t)wv * C + p * 64 + lane;
        float v = acc[p];
        if (MODE == 0) {
            out[idx] = v;
        } else {
            v += out[idx];
            if (MODE >= 2) {
                v = v * 0.25f + bias[p * 64 + lane];
                if (MODE == 2) v = fmaxf(v, 0.f);
            }
            out[idx] = v;
        }
    }
}

// ---------------------------------------------------------------------------

static inline size_t align256(size_t x) { return (x + 255) & ~(size_t)255; }

extern "C" void kernel_launch(void* const* d_in, const int* in_sizes, int n_in,
                              void* d_out, int out_size, void* d_ws, size_t ws_size,
                              hipStream_t stream) {
    const float* x  = (const float*)d_in[0];
    const int*   ei = (const int*)d_in[1];
    const int N  = in_sizes[0] / 9;
    const int E  = in_sizes[1] / 2;
    const int EP = E + N;
    const int* src = ei;
    const int* dst = ei + E;

    const float *Wl[3], *bl[3], *Wr[3], *br[3], *att[3], *bb[3];
    for (int i = 0; i < 3; i++) {
        Wl[i]  = (const float*)d_in[2 + 6 * i];
        bl[i]  = (const float*)d_in[3 + 6 * i];
        Wr[i]  = (const float*)d_in[4 + 6 * i];
        br[i]  = (const float*)d_in[5 + 6 * i];
        att[i] = (const float*)d_in[6 + 6 * i];
        bb[i]  = (const float*)d_in[7 + 6 * i];
    }

    // workspace layout
    char* w = (char*)d_ws;
    float* xl = (float*)w;  w += align256((size_t)N * 128 * 4);
    float* xr = (float*)w;  w += align256((size_t)N * 128 * 4);
    float* hA = (float*)w;  w += align256((size_t)N * 64 * 4);
    float* hB = (float*)w;  w += align256((size_t)N * 64 * 4);
    float* logits = (float*)w; w += align256((size_t)EP * 4);
    int* offs   = (int*)w;  w += align256((size_t)(N + 1) * 4);
    int* cursor = (int*)w;  w += align256((size_t)N * 4);  // also used as cnt
    int* eidx   = (int*)w;  w += align256((size_t)EP * 4);
    int* partial = (int*)w; w += 4096;

    // ---- CSR build over dst ----
    int* cnt = cursor;
    zero_int_k<<<(N + 255) / 256, 256, 0, stream>>>(cnt, N);
    count_k<<<(EP + 255) / 256, 256, 0, stream>>>(dst, cnt, E, EP);
    int nb = (N + 1023) / 1024;
    scan1_k<<<nb, 1024, 0, stream>>>(cnt, offs, partial, N);
    scan2_k<<<1, 64, 0, stream>>>(partial, nb);
    scan3_k<<<nb, 1024, 0, stream>>>(offs, partial, N);
    copy_int_k<<<(N + 255) / 256, 256, 0, stream>>>(offs, cursor, N);
    fill_k<<<(EP + 255) / 256, 256, 0, stream>>>(dst, cursor, eidx, E, EP);

    const int edgeBlocks = (EP + 3) / 4;  // 4 waves / block
    const int nodeBlocks = (N + 3) / 4;

    // ---- layer driver ----
    auto layer = [&](int li, const float* X, int FIN, int C, float* out, bool relu) {
        const int HC = 4 * C;
        for (int h = 0; h < 4; h++) {
            const int colOff = h * C;
            // gemm: xl, xr
            if (FIN == 9 && C == 64) {
                gemm2_k<9, 64><<<(N + 31) / 32, 256, 0, stream>>>(
                    X, Wl[li], bl[li], Wr[li], br[li], xl, xr, N, HC, colOff);
            } else if (FIN == 64 && C == 64) {
                gemm2_k<64, 64><<<(N + 31) / 32, 256, 0, stream>>>(
                    X, Wl[li], bl[li], Wr[li], br[li], xl, xr, N, HC, colOff);
            } else {
                gemm2_k<64, 128><<<(N + 15) / 16, 256, 0, stream>>>(
                    X, Wl[li], bl[li], Wr[li], br[li], xl, xr, N, HC, colOff);
            }
            // edge logits
            if (C == 64)
                edge_logits_k<64><<<edgeBlocks, 256, 0, stream>>>(
                    xl, xr, src, dst, att[li] + colOff, logits, E, EP);
            else
                edge_logits_k<128><<<edgeBlocks, 256, 0, stream>>>(
                    xl, xr, src, dst, att[li] + colOff, logits, E, EP);
            // node pass
            int mode = (h == 0) ? 0 : (h < 3) ? 1 : (relu ? 2 : 3);
            if (C == 64) {
                switch (mode) {
                case 0: node_pass_k<64, 0><<<nodeBlocks, 256, 0, stream>>>(xl, logits, src, offs, eidx, bb[li], out, N, E); break;
                case 1: node_pass_k<64, 1><<<nodeBlocks, 256, 0, stream>>>(xl, logits, src, offs, eidx, bb[li], out, N, E); break;
                case 2: node_pass_k<64, 2><<<nodeBlocks, 256, 0, stream>>>(xl, logits, src, offs, eidx, bb[li], out, N, E); break;
                default: node_pass_k<64, 3><<<nodeBlocks, 256, 0, stream>>>(xl, logits, src, offs, eidx, bb[li], out, N, E); break;
                }
            } else {
                switch (mode) {
                case 0: node_pass_k<128, 0><<<nodeBlocks, 256, 0, stream>>>(xl, logits, src, offs, eidx, bb[li], out, N, E); break;
                case 1: node_pass_k<128, 1><<<nodeBlocks, 256, 0, stream>>>(xl, logits, src, offs, eidx, bb[li], out, N, E); break;
                case 2: node_pass_k<128, 2><<<nodeBlocks, 256, 0, stream>>>(xl, logits, src, offs, eidx, bb[li], out, N, E); break;
                default: node_pass_k<128, 3><<<nodeBlocks, 256, 0, stream>>>(xl, logits, src, offs, eidx, bb[li], out, N, E); break;
                }
            }
        }
    };

    layer(0, x, 9, 64, hA, true);
    layer(1, hA, 64, 64, hB, true);
    layer(2, hB, 64, 128, (float*)d_out, false);
}

// Round 3
// 552.460 us; speedup vs baseline: 4.7969x; 4.7969x over previous
//
#include <hip/hip_runtime.h>
#include <hip/hip_bf16.h>

// ---------------------------------------------------------------------------
// MultiHopGATv2, fused formulation.
// Per layer:
//   gemm_bf16 x2 : xl = X@Wl+bl, xr = X@Wr+br  -> bf16 [N, H*C]
//   node_fused   : per dst node (1 wave), online-softmax over incoming edges:
//                  gather xl[src] row once, logits for all 4 heads via
//                  16-lane-group shfl reduce, running (m,s,acc), then
//                  head-mean + bias (+relu) -> fp32 [N, C]
// CSR over dst (storing src values directly) built once per call.
// ---------------------------------------------------------------------------

__device__ __forceinline__ float bflo(unsigned w) { return __uint_as_float(w << 16); }
__device__ __forceinline__ float bfhi(unsigned w) { return __uint_as_float(w & 0xffff0000u); }
__device__ __forceinline__ unsigned short f2bf(float v) {
    unsigned u = __float_as_uint(v);
    u = (u + 0x7fff + ((u >> 16) & 1)) >> 16;   // round-to-nearest-even
    return (unsigned short)u;
}

// ---------------- CSR build ----------------

__global__ void zero_int_k(int* p, int n) {
    int i = blockIdx.x * 256 + threadIdx.x;
    if (i < n) p[i] = 0;
}

__global__ void count_k(const int* __restrict__ dst, int* __restrict__ cnt,
                        int E, int EP) {
    int e = blockIdx.x * 256 + threadIdx.x;
    if (e >= EP) return;
    int d = (e < E) ? dst[e] : (e - E);
    atomicAdd(&cnt[d], 1);
}

__global__ void scan1_k(const int* __restrict__ cnt, int* __restrict__ offs,
                        int* __restrict__ partial, int N) {
    __shared__ int buf[2][1024];
    int g = blockIdx.x * 1024 + threadIdx.x;
    int v = (g < N) ? cnt[g] : 0;
    int pi = 0;
    buf[0][threadIdx.x] = v;
    __syncthreads();
    for (int s = 1; s < 1024; s <<= 1) {
        int t = buf[pi][threadIdx.x];
        if ((int)threadIdx.x >= s) t += buf[pi][threadIdx.x - s];
        buf[pi ^ 1][threadIdx.x] = t;
        pi ^= 1;
        __syncthreads();
    }
    int incl = buf[pi][threadIdx.x];
    if (g < N) offs[g + 1] = incl;
    if (threadIdx.x == 1023) partial[blockIdx.x] = incl;
}

__global__ void scan2_k(int* partial, int nb) {
    if (blockIdx.x == 0 && threadIdx.x == 0) {
        int run = 0;
        for (int i = 0; i < nb; i++) { int t = partial[i]; partial[i] = run; run += t; }
    }
}

__global__ void scan3_k(int* __restrict__ offs, const int* __restrict__ partial, int N) {
    int g = blockIdx.x * 1024 + threadIdx.x;
    if (g < N) offs[g + 1] += partial[blockIdx.x];
    if (g == 0) offs[0] = 0;
}

__global__ void copy_int_k(const int* __restrict__ a, int* __restrict__ b, int n) {
    int i = blockIdx.x * 256 + threadIdx.x;
    if (i < n) b[i] = a[i];
}

// store src VALUES in CSR order (no eidx indirection later)
__global__ void fill_k(const int* __restrict__ src, const int* __restrict__ dst,
                       int* __restrict__ cursor, int* __restrict__ csrc,
                       int E, int EP) {
    int e = blockIdx.x * 256 + threadIdx.x;
    if (e >= EP) return;
    int sv, d;
    if (e < E) { sv = src[e]; d = dst[e]; }
    else       { sv = e - E;  d = sv; }
    int p = atomicAdd(&cursor[d], 1);
    csrc[p] = sv;
}

// ---------------- dense transform: Y[N, HCT] = X@W + b  (bf16 out) ----------------
// CPT = columns per thread (HCT = 256*CPT). 8 rows per block, 256 threads.
template <int FIN, int CPT>
__global__ void gemm_bf16_k(const float* __restrict__ X, const float* __restrict__ W,
                            const float* __restrict__ b, unsigned short* __restrict__ Y,
                            int N) {
    constexpr int HCT = 256 * CPT;
    constexpr int RPT = 8;
    __shared__ float Xs[RPT][FIN];
    int tid  = threadIdx.x;
    int row0 = blockIdx.x * RPT;
    for (int i = tid; i < RPT * FIN; i += 256) {
        int r = i / FIN, k = i % FIN;
        int gr = row0 + r;
        Xs[r][k] = (gr < N) ? X[(size_t)gr * FIN + k] : 0.f;
    }
    __syncthreads();
    float acc[CPT][RPT];
#pragma unroll
    for (int c = 0; c < CPT; c++) {
        float bb = b[tid + 256 * c];
#pragma unroll
        for (int r = 0; r < RPT; r++) acc[c][r] = bb;
    }
    for (int k = 0; k < FIN; k++) {
        float w[CPT];
#pragma unroll
        for (int c = 0; c < CPT; c++) w[c] = W[(size_t)k * HCT + tid + 256 * c];
#pragma unroll
        for (int r = 0; r < RPT; r++) {
            float xv = Xs[r][k];
#pragma unroll
            for (int c = 0; c < CPT; c++) acc[c][r] = fmaf(xv, w[c], acc[c][r]);
        }
    }
#pragma unroll
    for (int r = 0; r < RPT; r++) {
        int gr = row0 + r;
        if (gr < N) {
#pragma unroll
            for (int c = 0; c < CPT; c++)
                Y[(size_t)gr * HCT + tid + 256 * c] = f2bf(acc[c][r]);
        }
    }
}

// ---------------- fused node pass ----------------
// One wave per dst node. F floats per lane (HCT = 64*F, C = 16*F).
// Lane l owns channels [l*F, l*F+F) of the H*C row; head = l>>4.
template <int F, bool RELU>
__global__ void node_fused_k(const unsigned short* __restrict__ xl,
                             const unsigned short* __restrict__ xr,
                             const float* __restrict__ att, const float* __restrict__ bias,
                             const int* __restrict__ offs, const int* __restrict__ csrc,
                             float* __restrict__ out, int N) {
    constexpr int HCT = 64 * F;
    int wv   = blockIdx.x * 4 + (threadIdx.x >> 6);
    int lane = threadIdx.x & 63;
    if (wv >= N) return;

    float xrv[F], at[F];
    {
        const unsigned* xp = (const unsigned*)(xr + (size_t)wv * HCT + lane * F);
#pragma unroll
        for (int i = 0; i < F / 2; i++) {
            unsigned w = xp[i];
            xrv[2 * i] = bflo(w); xrv[2 * i + 1] = bfhi(w);
        }
#pragma unroll
        for (int i = 0; i < F; i++) at[i] = att[lane * F + i];
    }

    int o0 = offs[wv], o1 = offs[wv + 1];
    float m = -1e30f, s = 0.f;
    float acc[F];
#pragma unroll
    for (int i = 0; i < F; i++) acc[i] = 0.f;

    for (int j = o0; j < o1; ++j) {
        int sn = csrc[j];
        const unsigned* xp = (const unsigned*)(xl + (size_t)sn * HCT + lane * F);
        float xv[F];
#pragma unroll
        for (int i = 0; i < F / 2; i++) {
            unsigned w = xp[i];
            xv[2 * i] = bflo(w); xv[2 * i + 1] = bfhi(w);
        }
        float p = 0.f;
#pragma unroll
        for (int i = 0; i < F; i++) {
            float e = xv[i] + xrv[i];
            e = (e > 0.f) ? e : 0.2f * e;
            p = fmaf(e, at[i], p);
        }
        // reduce within 16-lane head group
        p += __shfl_xor(p, 1, 64);
        p += __shfl_xor(p, 2, 64);
        p += __shfl_xor(p, 4, 64);
        p += __shfl_xor(p, 8, 64);
        // online softmax update (branchless)
        float nm = fmaxf(m, p);
        float r  = __expf(m - nm);
        float w  = __expf(p - nm);
        s = fmaf(s, r, w);
#pragma unroll
        for (int i = 0; i < F; i++) acc[i] = fmaf(acc[i], r, w * xv[i]);
        m = nm;
    }

    float inv = 1.f / s;
#pragma unroll
    for (int i = 0; i < F; i++) acc[i] *= inv;
    // sum over heads (stride-16 lanes hold the 4 heads' copies of each channel)
#pragma unroll
    for (int i = 0; i < F; i++) {
        acc[i] += __shfl_xor(acc[i], 16, 64);
        acc[i] += __shfl_xor(acc[i], 32, 64);
    }
    if (lane < 16) {
        float* op = out + (size_t)wv * (16 * F) + lane * F;
#pragma unroll
        for (int i = 0; i < F; i++) {
            float v = fmaf(acc[i], 0.25f, bias[lane * F + i]);
            if (RELU) v = fmaxf(v, 0.f);
            op[i] = v;
        }
    }
}

// ---------------------------------------------------------------------------

static inline size_t align256(size_t x) { return (x + 255) & ~(size_t)255; }

extern "C" void kernel_launch(void* const* d_in, const int* in_sizes, int n_in,
                              void* d_out, int out_size, void* d_ws, size_t ws_size,
                              hipStream_t stream) {
    const float* x  = (const float*)d_in[0];
    const int*   ei = (const int*)d_in[1];
    const int N  = in_sizes[0] / 9;
    const int E  = in_sizes[1] / 2;
    const int EP = E + N;
    const int* src = ei;
    const int* dst = ei + E;

    const float *Wl[3], *bl[3], *Wr[3], *br[3], *att[3], *bb[3];
    for (int i = 0; i < 3; i++) {
        Wl[i]  = (const float*)d_in[2 + 6 * i];
        bl[i]  = (const float*)d_in[3 + 6 * i];
        Wr[i]  = (const float*)d_in[4 + 6 * i];
        br[i]  = (const float*)d_in[5 + 6 * i];
        att[i] = (const float*)d_in[6 + 6 * i];
        bb[i]  = (const float*)d_in[7 + 6 * i];
    }

    // workspace layout (~119 MB)
    char* w = (char*)d_ws;
    unsigned short* xl = (unsigned short*)w; w += align256((size_t)N * 512 * 2);
    unsigned short* xr = (unsigned short*)w; w += align256((size_t)N * 512 * 2);
    float* hA = (float*)w;   w += align256((size_t)N * 64 * 4);
    float* hB = (float*)w;   w += align256((size_t)N * 64 * 4);
    int* offs   = (int*)w;   w += align256((size_t)(N + 1) * 4);
    int* cursor = (int*)w;   w += align256((size_t)N * 4);
    int* csrc   = (int*)w;   w += align256((size_t)EP * 4);
    int* partial = (int*)w;  w += 4096;

    // ---- CSR build over dst ----
    int* cnt = cursor;
    zero_int_k<<<(N + 255) / 256, 256, 0, stream>>>(cnt, N);
    count_k<<<(EP + 255) / 256, 256, 0, stream>>>(dst, cnt, E, EP);
    int nb = (N + 1023) / 1024;
    scan1_k<<<nb, 1024, 0, stream>>>(cnt, offs, partial, N);
    scan2_k<<<1, 64, 0, stream>>>(partial, nb);
    scan3_k<<<nb, 1024, 0, stream>>>(offs, partial, N);
    copy_int_k<<<(N + 255) / 256, 256, 0, stream>>>(offs, cursor, N);
    fill_k<<<(EP + 255) / 256, 256, 0, stream>>>(src, dst, cursor, csrc, E, EP);

    const int gemmBlocks = (N + 7) / 8;
    const int nodeBlocks = (N + 3) / 4;

    // ---- layer 0: 9 -> 64 (H*C = 256), relu ----
    gemm_bf16_k<9, 1><<<gemmBlocks, 256, 0, stream>>>(x, Wl[0], bl[0], xl, N);
    gemm_bf16_k<9, 1><<<gemmBlocks, 256, 0, stream>>>(x, Wr[0], br[0], xr, N);
    node_fused_k<4, true><<<nodeBlocks, 256, 0, stream>>>(
        xl, xr, att[0], bb[0], offs, csrc, hA, N);

    // ---- layer 1: 64 -> 64 (H*C = 256), relu ----
    gemm_bf16_k<64, 1><<<gemmBlocks, 256, 0, stream>>>(hA, Wl[1], bl[1], xl, N);
    gemm_bf16_k<64, 1><<<gemmBlocks, 256, 0, stream>>>(hA, Wr[1], br[1], xr, N);
    node_fused_k<4, true><<<nodeBlocks, 256, 0, stream>>>(
        xl, xr, att[1], bb[1], offs, csrc, hB, N);

    // ---- layer 2: 64 -> 128 (H*C = 512), no relu ----
    gemm_bf16_k<64, 2><<<gemmBlocks, 256, 0, stream>>>(hB, Wl[2], bl[2], xl, N);
    gemm_bf16_k<64, 2><<<gemmBlocks, 256, 0, stream>>>(hB, Wr[2], br[2], xr, N);
    node_fused_k<8, false><<<nodeBlocks, 256, 0, stream>>>(
        xl, xr, att[2], bb[2], offs, csrc, (float*)d_out, N);
}